// Round 1
// baseline (246.622 us; speedup 1.0000x reference)
//
#include <hip/hip_runtime.h>
#include <hip/hip_bf16.h>

// MoE: B=4096 tokens, D=256, H=1024, E=8 experts, one expert per token.
// Plan: (1) bin tokens by expert via atomics into d_ws; (2) fused per-expert
// MLP: per 64-token tile, loop over H in chunks of 32:
//   h_chunk = relu(x_tile @ W1[:,hc] + b1[hc])   (MFMA bf16 16x16x32, K=256)
//   y_tile += h_chunk @ W2[hc,:]                 (MFMA bf16, K=32)
// epilogue: out[token] = y + b2.

#define B_TOK 4096
#define D_DIM 256
#define H_DIM 1024
#define E_NUM 8
#define BM 64
#define HC 32
#define XP 264    // x_t / w1t row stride in bf16 elems (256 + 8 pad)
#define HTP 40    // ht / w2t row stride (32 + 8 pad)

typedef __attribute__((ext_vector_type(8))) short short8;
typedef __attribute__((ext_vector_type(4))) float f32x4;

__device__ __forceinline__ unsigned short f2bf(float f) {
    unsigned u = __builtin_bit_cast(unsigned, f);
    u = (u + 0x7fffu + ((u >> 16) & 1u)) >> 16;   // RNE
    return (unsigned short)u;
}

__global__ void bin_kernel(const int* __restrict__ eidx, int* cnt, int* bucket) {
    int t = blockIdx.x * blockDim.x + threadIdx.x;
    if (t < B_TOK) {
        int e = eidx[t];
        int p = atomicAdd(&cnt[e], 1);
        bucket[e * B_TOK + p] = t;
    }
}

__global__ __launch_bounds__(256, 2) void moe_kernel(
    const float* __restrict__ x, const float* __restrict__ W1,
    const float* __restrict__ b1, const float* __restrict__ W2,
    const float* __restrict__ b2, const int* __restrict__ cnt,
    const int* __restrict__ bucket, float* __restrict__ out)
{
    __shared__ unsigned short x_t[BM * XP];      // [m][d]  33792 B
    __shared__ unsigned short w1t[HC * XP];      // [h][d]  16896 B (transposed chunk)
    __shared__ unsigned short ht[BM * HTP];      // [m][h]   5120 B
    __shared__ unsigned short w2t[D_DIM * HTP];  // [d][h]  20480 B (transposed chunk)

    const int e = blockIdx.x >> 6;      // 64 tiles per expert
    const int tile = blockIdx.x & 63;
    const int n = cnt[e];
    const int row0 = tile * BM;
    if (row0 >= n) return;

    const int tid = threadIdx.x;
    const int w = tid >> 6;             // wave 0..3, owns output rows w*16..w*16+15
    const int L = tid & 63;
    const int l15 = L & 15;
    const int l4 = L >> 4;

    const float* W1e = W1 + (size_t)e * D_DIM * H_DIM;   // [d][h]
    const float* W2e = W2 + (size_t)e * H_DIM * D_DIM;   // [h][d]
    const int* buck = bucket + e * B_TOK;

    // ---- stage x tile (once): thread -> row r = tid/4, quarter q = tid%4
    {
        int r = tid >> 2, q = tid & 3;
        bool valid = (row0 + r) < n;
        const float* src = valid ? (x + (size_t)buck[row0 + r] * D_DIM + q * 64) : x;
        unsigned short* dst = &x_t[r * XP + q * 64];
        #pragma unroll
        for (int j = 0; j < 16; ++j) {
            float4 v = valid ? *(const float4*)(src + j * 4) : float4{0.f, 0.f, 0.f, 0.f};
            unsigned long long pk = (unsigned long long)f2bf(v.x)
                                  | ((unsigned long long)f2bf(v.y) << 16)
                                  | ((unsigned long long)f2bf(v.z) << 32)
                                  | ((unsigned long long)f2bf(v.w) << 48);
            *(unsigned long long*)(dst + j * 4) = pk;
        }
    }

    f32x4 acc2[16];
    #pragma unroll
    for (int i = 0; i < 16; ++i) acc2[i] = (f32x4){0.f, 0.f, 0.f, 0.f};

    for (int hc = 0; hc < H_DIM; hc += HC) {
        __syncthreads();   // previous iteration's LDS reads (and x stage) complete

        // ---- stage W1 chunk [256d x 32h] fp32 -> w1t[h][d] bf16 (transposed)
        {
            int f4 = tid & 7, dr = tid >> 3;        // f4: which float4 in row, dr: 0..31
            #pragma unroll
            for (int p = 0; p < 8; ++p) {
                int d = p * 32 + dr;
                float4 v = *(const float4*)(W1e + (size_t)d * H_DIM + hc + f4 * 4);
                int h0 = f4 * 4;
                w1t[(h0 + 0) * XP + d] = f2bf(v.x);
                w1t[(h0 + 1) * XP + d] = f2bf(v.y);
                w1t[(h0 + 2) * XP + d] = f2bf(v.z);
                w1t[(h0 + 3) * XP + d] = f2bf(v.w);
            }
        }
        // ---- stage W2 chunk [32h x 256d] fp32 -> w2t[d][h] bf16 (transposed)
        {
            int f4 = tid & 63, hr = tid >> 6;       // hr: 0..3
            #pragma unroll
            for (int p = 0; p < 8; ++p) {
                int h = p * 4 + hr;
                float4 v = *(const float4*)(W2e + (size_t)(hc + h) * D_DIM + f4 * 4);
                int d0 = f4 * 4;
                w2t[(d0 + 0) * HTP + h] = f2bf(v.x);
                w2t[(d0 + 1) * HTP + h] = f2bf(v.y);
                w2t[(d0 + 2) * HTP + h] = f2bf(v.z);
                w2t[(d0 + 3) * HTP + h] = f2bf(v.w);
            }
        }
        __syncthreads();

        // ---- GEMM1: h[m][hl] = sum_d x[m][d]*W1[d][hl], m in wave's 16 rows, hl 0..31
        f32x4 acc1[2];
        acc1[0] = (f32x4){0.f, 0.f, 0.f, 0.f};
        acc1[1] = (f32x4){0.f, 0.f, 0.f, 0.f};
        const unsigned short* xrow = &x_t[(w * 16 + l15) * XP + l4 * 8];
        #pragma unroll
        for (int kk = 0; kk < 8; ++kk) {
            short8 a = *(const short8*)(xrow + kk * 32);
            #pragma unroll
            for (int cf = 0; cf < 2; ++cf) {
                short8 b = *(const short8*)&w1t[(cf * 16 + l15) * XP + kk * 32 + l4 * 8];
                acc1[cf] = __builtin_amdgcn_mfma_f32_16x16x32_bf16(a, b, acc1[cf], 0, 0, 0);
            }
        }
        // bias + relu -> ht[m][hl] (C/D layout: row=(L>>4)*4+r, col=L&15)
        #pragma unroll
        for (int cf = 0; cf < 2; ++cf) {
            int hl = cf * 16 + l15;
            float bias = b1[e * H_DIM + hc + hl];
            #pragma unroll
            for (int r = 0; r < 4; ++r) {
                int m = w * 16 + l4 * 4 + r;
                float hv = acc1[cf][r] + bias;
                hv = hv > 0.f ? hv : 0.f;
                ht[m * HTP + hl] = f2bf(hv);
            }
        }
        __syncthreads();

        // ---- GEMM2: y[m][d] += sum_h ht[m][h]*W2[h][d], K=32 (one MFMA per col frag)
        short8 a2 = *(const short8*)&ht[(w * 16 + l15) * HTP + l4 * 8];
        #pragma unroll
        for (int cf = 0; cf < 16; ++cf) {
            short8 b = *(const short8*)&w2t[(cf * 16 + l15) * HTP + l4 * 8];
            acc2[cf] = __builtin_amdgcn_mfma_f32_16x16x32_bf16(a2, b, acc2[cf], 0, 0, 0);
        }
    }

    // ---- epilogue: out[token][d] = acc2 + b2
    const float* b2e = b2 + e * D_DIM;
    #pragma unroll
    for (int r = 0; r < 4; ++r) {
        int m = w * 16 + l4 * 4 + r;
        if (row0 + m < n) {
            int token = buck[row0 + m];
            float* orow = out + (size_t)token * D_DIM;
            #pragma unroll
            for (int cf = 0; cf < 16; ++cf) {
                int d = cf * 16 + l15;
                orow[d] = acc2[cf][r] + b2e[d];
            }
        }
    }
}

extern "C" void kernel_launch(void* const* d_in, const int* in_sizes, int n_in,
                              void* d_out, int out_size, void* d_ws, size_t ws_size,
                              hipStream_t stream) {
    const float* x  = (const float*)d_in[0];
    const float* W1 = (const float*)d_in[1];
    const float* b1 = (const float*)d_in[2];
    const float* W2 = (const float*)d_in[3];
    const float* b2 = (const float*)d_in[4];
    const int* eidx = (const int*)d_in[5];
    float* out = (float*)d_out;

    int* cnt = (int*)d_ws;                 // 8 counters (64 B reserved)
    int* bucket = (int*)d_ws + 16;         // E * B token indices = 128 KB

    hipMemsetAsync(cnt, 0, 16 * sizeof(int), stream);
    bin_kernel<<<B_TOK / 256, 256, 0, stream>>>(eidx, cnt, bucket);
    moe_kernel<<<E_NUM * 64, 256, 0, stream>>>(x, W1, b1, W2, b2, cnt, bucket, out);
}

// Round 2
// 58.297 us; speedup vs baseline: 4.2304x; 4.2304x over previous
//
#include <hip/hip_runtime.h>

// MoE B=4096, D=256, H=1024, E=8. Pipeline:
//  K0 memset cnt; K1 bin tokens; K2 gather x->bf16 xg[e][pos][D];
//  K3 transpose W1->w1t[e][h][d] bf16, W2->w2t[e][d][h] bf16;
//  K4 GEMM1: h = relu(xg @ w1t^T + b1) -> hw[e][pos][H] bf16  (grid 8x16x16)
//  K5 GEMM2: out[token] = hw @ w2t^T + b2                     (grid 8x16x4)

#define D_DIM 256
#define H_DIM 1024
#define E_NUM 8
#define B_TOK 4096
#define CAP   1024   // per-expert row capacity

typedef __attribute__((ext_vector_type(8))) short short8;
typedef __attribute__((ext_vector_type(4))) float f32x4;
typedef unsigned short u16;
typedef unsigned int u32;
typedef unsigned long long u64;

// ws layout (bytes)
#define CNT_OFF    0
#define BUCKET_OFF 1024
#define XG_OFF     (BUCKET_OFF + E_NUM*B_TOK*4)            // 132096
#define W1T_OFF    (XG_OFF  + (size_t)E_NUM*CAP*D_DIM*2)   // +4MB
#define W2T_OFF    (W1T_OFF + (size_t)E_NUM*H_DIM*D_DIM*2) // +4MB
#define HW_OFF     (W2T_OFF + (size_t)E_NUM*D_DIM*H_DIM*2) // +4MB, hw=16MB

__device__ __forceinline__ u16 f2bf(float f) {
    u32 u = __builtin_bit_cast(u32, f);
    u = (u + 0x7fffu + ((u >> 16) & 1u)) >> 16;  // RNE
    return (u16)u;
}

__global__ void bin_kernel(const int* __restrict__ eidx, int* cnt, int* bucket) {
    int t = blockIdx.x * 256 + threadIdx.x;
    if (t < B_TOK) {
        int e = eidx[t];
        int p = atomicAdd(&cnt[e], 1);
        if (p < B_TOK) bucket[e * B_TOK + p] = t;
    }
}

// one wave per (e,pos) row: gather token row, fp32->bf16, zero-fill invalid rows
__global__ void gather_kernel(const float* __restrict__ x, const int* __restrict__ cnt,
                              const int* __restrict__ bucket, u16* __restrict__ xg) {
    int row = blockIdx.x * 4 + (threadIdx.x >> 6);
    int lane = threadIdx.x & 63;
    int e = row >> 10, pos = row & (CAP - 1);
    int n = min(cnt[e], CAP);
    u64 pk = 0;
    if (pos < n) {
        int t = bucket[e * B_TOK + pos];
        float4 v = *(const float4*)(x + (size_t)t * D_DIM + lane * 4);
        pk = (u64)f2bf(v.x) | ((u64)f2bf(v.y) << 16)
           | ((u64)f2bf(v.z) << 32) | ((u64)f2bf(v.w) << 48);
    }
    *(u64*)&xg[(size_t)row * D_DIM + lane * 4] = pk;
}

// 64x64 tile transpose fp32[R][C] -> bf16[C][R]; bid<512: W1, else W2
__global__ void wtrans_kernel(const float* __restrict__ W1, const float* __restrict__ W2,
                              u16* __restrict__ w1t, u16* __restrict__ w2t) {
    __shared__ u16 tile[64 * 68];
    int b = blockIdx.x, tid = threadIdx.x;
    const float* in; u16* outp; int R, C, rt, ct;
    if (b < 512) {
        int e = b >> 6, t = b & 63;
        in = W1 + (size_t)e * D_DIM * H_DIM; outp = w1t + (size_t)e * H_DIM * D_DIM;
        R = D_DIM; C = H_DIM; rt = t >> 4; ct = t & 15;
    } else {
        int e = (b - 512) >> 6, t = (b - 512) & 63;
        in = W2 + (size_t)e * H_DIM * D_DIM; outp = w2t + (size_t)e * D_DIM * H_DIM;
        R = H_DIM; C = D_DIM; rt = t >> 2; ct = t & 3;
    }
    #pragma unroll
    for (int it = 0; it < 4; ++it) {
        int r = it * 16 + (tid >> 4);
        int c4 = (tid & 15) * 4;
        float4 v = *(const float4*)(in + (size_t)(rt * 64 + r) * C + ct * 64 + c4);
        u64 pk = (u64)f2bf(v.x) | ((u64)f2bf(v.y) << 16)
               | ((u64)f2bf(v.z) << 32) | ((u64)f2bf(v.w) << 48);
        *(u64*)&tile[r * 68 + c4] = pk;
    }
    __syncthreads();
    #pragma unroll
    for (int it = 0; it < 2; ++it) {
        int oc = it * 32 + (tid >> 3);       // output row (global col)
        int r0 = (tid & 7) * 8;              // 8 consecutive output elems
        u32 p0 = tile[(r0 + 0) * 68 + oc] | ((u32)tile[(r0 + 1) * 68 + oc] << 16);
        u32 p1 = tile[(r0 + 2) * 68 + oc] | ((u32)tile[(r0 + 3) * 68 + oc] << 16);
        u32 p2 = tile[(r0 + 4) * 68 + oc] | ((u32)tile[(r0 + 5) * 68 + oc] << 16);
        u32 p3 = tile[(r0 + 6) * 68 + oc] | ((u32)tile[(r0 + 7) * 68 + oc] << 16);
        *(uint4*)(outp + (size_t)(ct * 64 + oc) * R + rt * 64 + r0) = uint4{p0, p1, p2, p3};
    }
}

// GEMM1: block = (e, tile of 64 tokens, h-chunk of 64). M=64,N=64,K=256.
__global__ __launch_bounds__(256, 2) void gemm1_kernel(
    const u16* __restrict__ xg, const u16* __restrict__ w1t,
    const float* __restrict__ b1, const int* __restrict__ cnt,
    u16* __restrict__ hw)
{
    __shared__ u16 xs[64 * 264];
    __shared__ u16 w1s[64 * 264];
    __shared__ u16 hs[64 * 72];

    int b = blockIdx.x;
    int e = b >> 8, tile = (b >> 4) & 15, hch = b & 15;
    int n = min(cnt[e], CAP);
    if (tile * 64 >= n) return;

    int tid = threadIdx.x;
    int w = tid >> 6, L = tid & 63, l15 = L & 15, l4 = L >> 4;
    int wr = (w >> 1) * 32, wc = (w & 1) * 32;

    {
        const u16* gx = xg + ((size_t)e * CAP + tile * 64) * D_DIM;
        const u16* gw = w1t + ((size_t)e * H_DIM + hch * 64) * D_DIM;
        int rr = tid >> 5, cc = (tid & 31) * 8;
        #pragma unroll
        for (int it = 0; it < 8; ++it) {
            int row = it * 8 + rr;
            *(short8*)&xs[row * 264 + cc]  = *(const short8*)&gx[(size_t)row * D_DIM + cc];
            *(short8*)&w1s[row * 264 + cc] = *(const short8*)&gw[(size_t)row * D_DIM + cc];
        }
    }
    __syncthreads();

    f32x4 acc[2][2];
    #pragma unroll
    for (int i = 0; i < 2; ++i)
        #pragma unroll
        for (int j = 0; j < 2; ++j) acc[i][j] = (f32x4){0.f, 0.f, 0.f, 0.f};

    #pragma unroll
    for (int k = 0; k < 8; ++k) {
        short8 a0 = *(const short8*)&xs[(wr + l15) * 264 + k * 32 + l4 * 8];
        short8 a1 = *(const short8*)&xs[(wr + 16 + l15) * 264 + k * 32 + l4 * 8];
        short8 b0 = *(const short8*)&w1s[(wc + l15) * 264 + k * 32 + l4 * 8];
        short8 b1v = *(const short8*)&w1s[(wc + 16 + l15) * 264 + k * 32 + l4 * 8];
        acc[0][0] = __builtin_amdgcn_mfma_f32_16x16x32_bf16(a0, b0, acc[0][0], 0, 0, 0);
        acc[0][1] = __builtin_amdgcn_mfma_f32_16x16x32_bf16(a0, b1v, acc[0][1], 0, 0, 0);
        acc[1][0] = __builtin_amdgcn_mfma_f32_16x16x32_bf16(a1, b0, acc[1][0], 0, 0, 0);
        acc[1][1] = __builtin_amdgcn_mfma_f32_16x16x32_bf16(a1, b1v, acc[1][1], 0, 0, 0);
    }

    #pragma unroll
    for (int mr = 0; mr < 2; ++mr)
        #pragma unroll
        for (int nc = 0; nc < 2; ++nc) {
            float bias = b1[e * H_DIM + hch * 64 + wc + nc * 16 + l15];
            #pragma unroll
            for (int j = 0; j < 4; ++j) {
                float v = acc[mr][nc][j] + bias;
                v = v > 0.f ? v : 0.f;
                hs[(wr + mr * 16 + l4 * 4 + j) * 72 + wc + nc * 16 + l15] = f2bf(v);
            }
        }
    __syncthreads();
    {
        u16* gh = hw + ((size_t)e * CAP + tile * 64) * H_DIM + hch * 64;
        int rr8 = tid >> 3, off = (tid & 7) * 8;
        #pragma unroll
        for (int it = 0; it < 2; ++it) {
            int row = it * 32 + rr8;
            *(short8*)&gh[(size_t)row * H_DIM + off] = *(const short8*)&hs[row * 72 + off];
        }
    }
}

// GEMM2: block = (e, tile of 64 tokens, d-chunk of 64). M=64,N=64,K=1024 in 4 chunks.
__global__ __launch_bounds__(256, 2) void gemm2_kernel(
    const u16* __restrict__ hw, const u16* __restrict__ w2t,
    const float* __restrict__ b2, const int* __restrict__ cnt,
    const int* __restrict__ bucket, float* __restrict__ out)
{
    __shared__ u16 as_[64 * 264];
    __shared__ u16 bs[64 * 264];

    int b = blockIdx.x;
    int e = b >> 6, tile = (b >> 2) & 15, nch = b & 3;
    int n = min(cnt[e], CAP);
    if (tile * 64 >= n) return;

    int tid = threadIdx.x;
    int w = tid >> 6, L = tid & 63, l15 = L & 15, l4 = L >> 4;
    int wr = (w >> 1) * 32, wc = (w & 1) * 32;

    f32x4 acc[2][2];
    #pragma unroll
    for (int i = 0; i < 2; ++i)
        #pragma unroll
        for (int j = 0; j < 2; ++j) acc[i][j] = (f32x4){0.f, 0.f, 0.f, 0.f};

    const u16* ga = hw + ((size_t)e * CAP + tile * 64) * H_DIM;
    const u16* gb = w2t + ((size_t)e * D_DIM + nch * 64) * H_DIM;

    for (int kc = 0; kc < 4; ++kc) {
        __syncthreads();
        int rr = tid >> 5, cc = (tid & 31) * 8;
        #pragma unroll
        for (int it = 0; it < 8; ++it) {
            int row = it * 8 + rr;
            *(short8*)&as_[row * 264 + cc] = *(const short8*)&ga[(size_t)row * H_DIM + kc * 256 + cc];
            *(short8*)&bs[row * 264 + cc]  = *(const short8*)&gb[(size_t)row * H_DIM + kc * 256 + cc];
        }
        __syncthreads();
        #pragma unroll
        for (int k = 0; k < 8; ++k) {
            short8 a0 = *(const short8*)&as_[(wr + l15) * 264 + k * 32 + l4 * 8];
            short8 a1 = *(const short8*)&as_[(wr + 16 + l15) * 264 + k * 32 + l4 * 8];
            short8 b0 = *(const short8*)&bs[(wc + l15) * 264 + k * 32 + l4 * 8];
            short8 b1v = *(const short8*)&bs[(wc + 16 + l15) * 264 + k * 32 + l4 * 8];
            acc[0][0] = __builtin_amdgcn_mfma_f32_16x16x32_bf16(a0, b0, acc[0][0], 0, 0, 0);
            acc[0][1] = __builtin_amdgcn_mfma_f32_16x16x32_bf16(a0, b1v, acc[0][1], 0, 0, 0);
            acc[1][0] = __builtin_amdgcn_mfma_f32_16x16x32_bf16(a1, b0, acc[1][0], 0, 0, 0);
            acc[1][1] = __builtin_amdgcn_mfma_f32_16x16x32_bf16(a1, b1v, acc[1][1], 0, 0, 0);
        }
    }

    #pragma unroll
    for (int mr = 0; mr < 2; ++mr)
        #pragma unroll
        for (int j = 0; j < 4; ++j) {
            int m = wr + mr * 16 + l4 * 4 + j;
            if (tile * 64 + m < n) {
                int token = bucket[e * B_TOK + tile * 64 + m];
                #pragma unroll
                for (int nc = 0; nc < 2; ++nc) {
                    int d = nch * 64 + wc + nc * 16 + l15;
                    out[(size_t)token * D_DIM + d] = acc[mr][nc][j] + b2[e * D_DIM + d];
                }
            }
        }
}

extern "C" void kernel_launch(void* const* d_in, const int* in_sizes, int n_in,
                              void* d_out, int out_size, void* d_ws, size_t ws_size,
                              hipStream_t stream) {
    const float* x  = (const float*)d_in[0];
    const float* W1 = (const float*)d_in[1];
    const float* b1 = (const float*)d_in[2];
    const float* W2 = (const float*)d_in[3];
    const float* b2 = (const float*)d_in[4];
    const int* eidx = (const int*)d_in[5];
    float* out = (float*)d_out;

    char* ws = (char*)d_ws;
    int* cnt    = (int*)(ws + CNT_OFF);
    int* bucket = (int*)(ws + BUCKET_OFF);
    u16* xg     = (u16*)(ws + XG_OFF);
    u16* w1t    = (u16*)(ws + W1T_OFF);
    u16* w2t    = (u16*)(ws + W2T_OFF);
    u16* hw     = (u16*)(ws + HW_OFF);

    hipMemsetAsync(cnt, 0, 8 * sizeof(int), stream);
    bin_kernel<<<B_TOK / 256, 256, 0, stream>>>(eidx, cnt, bucket);
    gather_kernel<<<(E_NUM * CAP) / 4, 256, 0, stream>>>(x, cnt, bucket, xg);
    wtrans_kernel<<<1024, 256, 0, stream>>>(W1, W2, w1t, w2t);
    gemm1_kernel<<<E_NUM * 16 * 16, 256, 0, stream>>>(xg, w1t, b1, cnt, hw);
    gemm2_kernel<<<E_NUM * 16 * 4, 256, 0, stream>>>(hw, w2t, b2, cnt, bucket, out);
}